// Round 3
// baseline (636.607 us; speedup 1.0000x reference)
//
#include <hip/hip_runtime.h>
#include <math.h>

#define B_ROWS 32768
#define K_CODES 4096
#define D_DIM 128

// ---------------------------------------------------------------------------
// Kernel 1: e2 row sums of squares only (x2 is now computed inside vq_argmin).
// Replicates numpy pairwise_sum for n=128: 8 strided accumulators
// r[j] = sum_{i = j mod 8} fl(e_i*e_i), combined ((r0+r1)+(r2+r3))+((r4+r5)+(r6+r7)).
// ---------------------------------------------------------------------------
__global__ __launch_bounds__(256) void sq_rows_e(const float* __restrict__ emb,
                                                 float* __restrict__ e2) {
  int row = blockIdx.x * 32 + (threadIdx.x >> 3);
  int lane = threadIdx.x & 7;
  const float* src = emb + (size_t)row * D_DIM;
  float v = src[lane];
  float t = v * v;
  asm volatile("" : "+v"(t));  // block fma contraction: term must be fl(v*v)
  float acc = t;
#pragma unroll
  for (int i = 1; i < 16; ++i) {
    float w = src[i * 8 + lane];
    float tt = w * w;
    asm volatile("" : "+v"(tt));
    acc = acc + tt;
  }
  acc = acc + __shfl_xor(acc, 1, 64);
  acc = acc + __shfl_xor(acc, 2, 64);
  acc = acc + __shfl_xor(acc, 4, 64);
  if (lane == 0) e2[row] = acc;
}

// ---------------------------------------------------------------------------
// Kernel 2: fused GEMM + argmin.
// 512 threads (8 waves = 2/SIMD at 1 block/CU), 128-row tile.
// As[128d][128m] resident (64 KB), Bs[2][32d][256n] double-buffered (64 KB),
// e2s[4096] staged in LDS (16 KB), x2s[128] (0.5 KB).  ~145 KB total.
// d-loop is software-pipelined: fragments for d+1 are loaded into registers
// while d's 64 FMAs issue (launch_bounds(512,2) -> up to 256 VGPR).
// Numerics identical to the validated round-2 kernel: per-acc FMA chain is
// d = 0..127 ascending, single-rounded; score = fmaf(-2, dot, fl(x2+e2));
// argmin strict less-than, first index wins ties.
// ---------------------------------------------------------------------------
__global__ __launch_bounds__(512, 2) void vq_argmin(const float* __restrict__ x,
                                                    const float* __restrict__ emb,
                                                    const float* __restrict__ e2,
                                                    float* __restrict__ out_idx) {
  __shared__ float smem[128 * 128 + 2 * 32 * 256];  // As + Bs, 128 KB
  __shared__ float e2s[K_CODES];                    // 16 KB
  __shared__ float x2s[128];                        // 0.5 KB
  float* As = smem;                // [d][m]
  float* Bs = smem + 128 * 128;    // [buf][d][n]

  const int tid = threadIdx.x;
  const int tx = tid & 31;   // n-direction: 32 groups
  const int ty = tid >> 5;   // m-direction: 16 groups of 8 rows
  const int rowbase = blockIdx.x * 128;

  // ---- stage As: x[rowbase+m][d] -> As[d*128+m] (transpose; one-time) ----
  {
    int m = tid >> 2;        // 0..127
    int q = tid & 3;         // 32-d quarter
    const float4* src = (const float4*)(x + (size_t)(rowbase + m) * 128 + q * 32);
#pragma unroll
    for (int p = 0; p < 8; ++p) {
      float4 v = src[p];
      int d = q * 32 + p * 4;
      As[(d + 0) * 128 + m] = v.x;
      As[(d + 1) * 128 + m] = v.y;
      As[(d + 2) * 128 + m] = v.z;
      As[(d + 3) * 128 + m] = v.w;
    }
  }
  // ---- stage e2 -> LDS (16 KB), coalesced ----
  {
    ((float4*)e2s)[tid * 2] = ((const float4*)e2)[tid * 2];
    ((float4*)e2s)[tid * 2 + 1] = ((const float4*)e2)[tid * 2 + 1];
  }
  __syncthreads();

  // ---- x2 for this block's 128 rows, from As, numpy pairwise order ----
  // 8 lanes per row; accumulator j sums elements d = i*8+j (i=0..15),
  // shfl-xor 1,2,4 reproduces ((r0+r1)+(r2+r3))+((r4+r5)+(r6+r7)).
#pragma unroll
  for (int pass = 0; pass < 2; ++pass) {
    int r = pass * 64 + (tid >> 3);
    int j = tid & 7;
    float v = As[j * 128 + r];
    float t = v * v;
    asm volatile("" : "+v"(t));
    float a2 = t;
#pragma unroll
    for (int i = 1; i < 16; ++i) {
      float w = As[(i * 8 + j) * 128 + r];
      float tt = w * w;
      asm volatile("" : "+v"(tt));
      a2 = a2 + tt;
    }
    a2 = a2 + __shfl_xor(a2, 1, 64);
    a2 = a2 + __shfl_xor(a2, 2, 64);
    a2 = a2 + __shfl_xor(a2, 4, 64);
    if (j == 0) x2s[r] = a2;
  }
  __syncthreads();

  float xs2[8];
#pragma unroll
  for (int i = 0; i < 8; ++i) xs2[i] = x2s[ty * 8 + i];

  float minv[8];
  int mini[8];
#pragma unroll
  for (int i = 0; i < 8; ++i) { minv[i] = 3.4e38f; mini[i] = 0; }

  const int n = tid >> 1;   // code row within 256-chunk (0..255)
  const int h = tid & 1;    // which 16-d half of the 32-d slab
  float4 breg[4];

  // prefetch + store stage 0 (chunk 0, d-slab 0) into buf 0
  {
    const float4* src = (const float4*)(emb + (size_t)n * 128 + h * 16);
#pragma unroll
    for (int p = 0; p < 4; ++p) breg[p] = src[p];
#pragma unroll
    for (int p = 0; p < 4; ++p) {
      float* bp = Bs + (size_t)(h * 16 + p * 4) * 256 + n;
      bp[0] = breg[p].x; bp[256] = breg[p].y; bp[512] = breg[p].z; bp[768] = breg[p].w;
    }
  }

  float acc[8][8];
#pragma unroll
  for (int i = 0; i < 8; ++i)
#pragma unroll
    for (int j = 0; j < 8; ++j) acc[i][j] = 0.0f;

#pragma unroll 1
  for (int s = 0; s < 64; ++s) {   // s = chunk*4 + d-slab; chunk = 256 codes
    __syncthreads();
    if (s + 1 < 64) {  // prefetch next slab into regs (latency hidden by FMAs)
      int s1 = s + 1;
      const float4* src = (const float4*)(emb + (size_t)((s1 >> 2) * 256 + n) * 128 +
                                          (s1 & 3) * 32 + h * 16);
#pragma unroll
      for (int p = 0; p < 4; ++p) breg[p] = src[p];
    }
    const float* bbase = Bs + (size_t)(s & 1) * 8192;
    const float* abase = As + (size_t)(s & 3) * 32 * 128;

    // software-pipelined d-loop: load d+1 while FMA-ing d
    float4 A0 = *(const float4*)(abase + ty * 8);
    float4 A1 = *(const float4*)(abase + ty * 8 + 4);
    float4 B0 = *(const float4*)(bbase + tx * 4);
    float4 B1 = *(const float4*)(bbase + tx * 4 + 128);
#pragma unroll 4
    for (int d = 0; d < 31; ++d) {
      float4 A0n = *(const float4*)(abase + (d + 1) * 128 + ty * 8);
      float4 A1n = *(const float4*)(abase + (d + 1) * 128 + ty * 8 + 4);
      float4 B0n = *(const float4*)(bbase + (d + 1) * 256 + tx * 4);
      float4 B1n = *(const float4*)(bbase + (d + 1) * 256 + tx * 4 + 128);
      {
        const float av[8] = {A0.x, A0.y, A0.z, A0.w, A1.x, A1.y, A1.z, A1.w};
        const float bv[8] = {B0.x, B0.y, B0.z, B0.w, B1.x, B1.y, B1.z, B1.w};
#pragma unroll
        for (int i = 0; i < 8; ++i)
#pragma unroll
          for (int j = 0; j < 8; ++j)
            acc[i][j] = __builtin_fmaf(av[i], bv[j], acc[i][j]);
      }
      A0 = A0n; A1 = A1n; B0 = B0n; B1 = B1n;
    }
    {  // d = 31 epilogue of the pipeline
      const float av[8] = {A0.x, A0.y, A0.z, A0.w, A1.x, A1.y, A1.z, A1.w};
      const float bv[8] = {B0.x, B0.y, B0.z, B0.w, B1.x, B1.y, B1.z, B1.w};
#pragma unroll
      for (int i = 0; i < 8; ++i)
#pragma unroll
        for (int j = 0; j < 8; ++j)
          acc[i][j] = __builtin_fmaf(av[i], bv[j], acc[i][j]);
    }

    if (s + 1 < 64) {  // store prefetched slab into the other buffer
      float* bw = Bs + (size_t)((s + 1) & 1) * 8192;
#pragma unroll
      for (int p = 0; p < 4; ++p) {
        float* bp = bw + (size_t)(h * 16 + p * 4) * 256 + n;
        bp[0] = breg[p].x; bp[256] = breg[p].y; bp[512] = breg[p].z; bp[768] = breg[p].w;
      }
    }
    if ((s & 3) == 3) {  // chunk finished: score 256 codes, update argmin
      int kbase = (s >> 2) * 256;
      float4 ea = *(const float4*)(e2s + kbase + tx * 4);
      float4 eb = *(const float4*)(e2s + kbase + 128 + tx * 4);
      const float e2r[8] = {ea.x, ea.y, ea.z, ea.w, eb.x, eb.y, eb.z, eb.w};
#pragma unroll
      for (int i = 0; i < 8; ++i) {
#pragma unroll
        for (int j = 0; j < 8; ++j) {
          float t1 = xs2[i] + e2r[j];                       // fl(x2+e2)
          float dsc = __builtin_fmaf(-2.0f, acc[i][j], t1); // fl(t1 - 2*dot)
          int idx = kbase + (j < 4 ? tx * 4 + j : 128 + tx * 4 + (j - 4));
          if (dsc < minv[i]) { minv[i] = dsc; mini[i] = idx; }  // first idx wins ties
          acc[i][j] = 0.0f;
        }
      }
    }
  }

  // ---- cross-thread reduction: 32 candidates per row ----
  __syncthreads();
  float* redv = smem;                       // reuse As region: [128][32]
  int* redi = (int*)(smem + 128 * 32);      // [128][32]
#pragma unroll
  for (int i = 0; i < 8; ++i) {
    redv[(ty * 8 + i) * 32 + tx] = minv[i];
    redi[(ty * 8 + i) * 32 + tx] = mini[i];
  }
  __syncthreads();
  if (tid < 128) {
    int r = tid;
    float bv = redv[r * 32];
    int bi = redi[r * 32];
#pragma unroll
    for (int t = 1; t < 32; ++t) {
      float v = redv[r * 32 + t];
      int i2 = redi[r * 32 + t];
      if (v < bv || (v == bv && i2 < bi)) { bv = v; bi = i2; }
    }
    out_idx[rowbase + r] = (float)bi;
  }
}

// ---------------------------------------------------------------------------
// Kernel 3: gather + straight-through output + loss partials + histogram,
// with the finalize (vq_loss scalars + perplexity) fused via a device-scope
// done-counter: the last block to finish runs it (atomic reads for coherence).
// st = fl(x + fl(q-x)); e-term fl((q-x)^2), q-term fl((st-x)^2), double accum.
// ---------------------------------------------------------------------------
__global__ __launch_bounds__(256) void vq_gather(const float* __restrict__ x,
                                                 const float* __restrict__ emb,
                                                 const float* __restrict__ idxf,
                                                 float* __restrict__ out_q,
                                                 unsigned int* __restrict__ counts,
                                                 double* __restrict__ sums,
                                                 unsigned int* __restrict__ done,
                                                 float* __restrict__ out_scalars) {
  int r = blockIdx.x * 8 + (threadIdx.x >> 5);
  int lane = threadIdx.x & 31;
  int idx = (int)idxf[r];
  const float4 q = *(const float4*)(emb + (size_t)idx * 128 + lane * 4);
  const float4 xv = *(const float4*)(x + (size_t)r * 128 + lane * 4);
  float d0 = q.x - xv.x, d1 = q.y - xv.y, d2 = q.z - xv.z, d3 = q.w - xv.w;
  float s0 = xv.x + d0, s1 = xv.y + d1, s2 = xv.z + d2, s3 = xv.w + d3;
  float4 st = make_float4(s0, s1, s2, s3);
  *(float4*)(out_q + (size_t)r * 128 + lane * 4) = st;
  float g0 = s0 - xv.x, g1 = s1 - xv.y, g2 = s2 - xv.z, g3 = s3 - xv.w;
  double es = (double)(d0 * d0) + (double)(d1 * d1) + (double)(d2 * d2) + (double)(d3 * d3);
  double qs = (double)(g0 * g0) + (double)(g1 * g1) + (double)(g2 * g2) + (double)(g3 * g3);
#pragma unroll
  for (int off = 32; off >= 1; off >>= 1) {
    es += __shfl_down(es, off, 64);
    qs += __shfl_down(qs, off, 64);
  }
  __shared__ double lred[2][4];
  int w = threadIdx.x >> 6;
  if ((threadIdx.x & 63) == 0) { lred[0][w] = es; lred[1][w] = qs; }
  if (lane == 0) atomicAdd(&counts[idx], 1u);
  __syncthreads();
  if (threadIdx.x == 0) {
    double e = lred[0][0] + lred[0][1] + lred[0][2] + lred[0][3];
    double qq = lred[1][0] + lred[1][1] + lred[1][2] + lred[1][3];
    atomicAdd(&sums[0], e);
    atomicAdd(&sums[1], qq);
  }

  // ---- last-block finalize ----
  __shared__ unsigned int lastflag;
  if (threadIdx.x == 0) {
    __threadfence();
    unsigned int prev = atomicAdd(done, 1u);
    lastflag = (prev == gridDim.x - 1) ? 1u : 0u;
  }
  __syncthreads();
  if (lastflag) {
    double s = 0.0;
    for (int k = threadIdx.x; k < K_CODES; k += 256) {
      unsigned int c = atomicAdd(&counts[k], 0u);  // device-coherent read
      float p = (float)c * (1.0f / 32768.0f);      // exact pow2 divide
      float term = p * logf(p + 1e-10f);
      s += (double)term;
    }
#pragma unroll
    for (int off = 32; off >= 1; off >>= 1) s += __shfl_down(s, off, 64);
    __shared__ double red[4];
    if ((threadIdx.x & 63) == 0) red[threadIdx.x >> 6] = s;
    __syncthreads();
    if (threadIdx.x == 0) {
      double tot = red[0] + red[1] + red[2] + red[3];
      double e = atomicAdd(&sums[0], 0.0);
      double qq = atomicAdd(&sums[1], 0.0);
      float e_lat = (float)(e / (double)(B_ROWS * D_DIM));
      float q_lat = (float)(qq / (double)(B_ROWS * D_DIM));
      float vq = q_lat + 0.25f * e_lat;   // fl(q + fl(0.25*e)); 0.25*e exact
      out_scalars[0] = vq;
      out_scalars[1] = e_lat;
      out_scalars[2] = q_lat;
      out_scalars[3] = expf(-(float)tot);
    }
  }
}

extern "C" void kernel_launch(void* const* d_in, const int* in_sizes, int n_in,
                              void* d_out, int out_size, void* d_ws, size_t ws_size,
                              hipStream_t stream) {
  const float* x = (const float*)d_in[0];
  const float* emb = (const float*)d_in[1];
  float* out = (float*)d_out;

  // ws: counts[4096] u32 @0 | sums[2] f64 @16384 | done u32 @16400 | e2 @16416
  unsigned int* counts = (unsigned int*)d_ws;
  double* sums = (double*)((char*)d_ws + 16384);
  unsigned int* done = (unsigned int*)((char*)d_ws + 16400);
  float* e2 = (float*)((char*)d_ws + 16416);

  float* out_idx = out + (size_t)B_ROWS * D_DIM;
  float* out_scalars = out_idx + B_ROWS;

  hipMemsetAsync(d_ws, 0, 16416, stream);  // zero counts + sums + done
  sq_rows_e<<<K_CODES / 32, 256, 0, stream>>>(emb, e2);
  vq_argmin<<<B_ROWS / 128, 512, 0, stream>>>(x, emb, e2, out_idx);
  vq_gather<<<B_ROWS / 8, 256, 0, stream>>>(x, emb, out_idx, out, counts, sums,
                                            done, out_scalars);
}

// Round 4
// 524.402 us; speedup vs baseline: 1.2140x; 1.2140x over previous
//
#include <hip/hip_runtime.h>
#include <math.h>

#define B_ROWS 32768
#define K_CODES 4096
#define D_DIM 128
#define MARGIN 1.5e-3f
#define CAP 32

typedef short bf16x8 __attribute__((ext_vector_type(8)));
typedef float f32x4 __attribute__((ext_vector_type(4)));

// RNE float->bf16 (finite inputs only)
__device__ __forceinline__ unsigned short f2bf(float f) {
  union { float f; unsigned int u; } v; v.f = f;
  unsigned int r = (v.u + 0x7FFFu + ((v.u >> 16) & 1u)) >> 16;
  return (unsigned short)r;
}

// ---------------------------------------------------------------------------
// Kernel 0: cast x and emb to bf16 (RNE), written into d_out scratch region.
// ---------------------------------------------------------------------------
#define NX (B_ROWS * D_DIM)
#define NE (K_CODES * D_DIM)
__global__ __launch_bounds__(256) void cast_bf16(const float* __restrict__ x,
                                                 const float* __restrict__ emb,
                                                 unsigned short* __restrict__ xb,
                                                 unsigned short* __restrict__ eb) {
  int g = blockIdx.x * blockDim.x + threadIdx.x;  // one group = 8 elements
  const int NGX = NX / 8, NG = (NX + NE) / 8;
  for (; g < NG; g += gridDim.x * blockDim.x) {
    const float* src; unsigned short* dst; int off;
    if (g < NGX) { src = x; dst = xb; off = g * 8; }
    else { src = emb; dst = eb; off = (g - NGX) * 8; }
    float4 a = *(const float4*)(src + off);
    float4 b = *(const float4*)(src + off + 4);
    ushort4 o0 = make_ushort4(f2bf(a.x), f2bf(a.y), f2bf(a.z), f2bf(a.w));
    ushort4 o1 = make_ushort4(f2bf(b.x), f2bf(b.y), f2bf(b.z), f2bf(b.w));
    *(ushort4*)(dst + off) = o0;
    *(ushort4*)(dst + off + 4) = o1;
  }
}

// ---------------------------------------------------------------------------
// Kernel 1 (round-2 validated): x2 and e2 row sums of squares, numpy pairwise
// order for n=128: 8 strided accumulators, ((r0+r1)+(r2+r3))+((r4+r5)+(r6+r7)).
// ---------------------------------------------------------------------------
__global__ __launch_bounds__(256) void sq_rows(const float* __restrict__ x,
                                               const float* __restrict__ emb,
                                               float* __restrict__ x2,
                                               float* __restrict__ e2) {
  int row = blockIdx.x * 32 + (threadIdx.x >> 3);
  int lane = threadIdx.x & 7;
  const float* src;
  float* dst;
  if (row < B_ROWS) {
    src = x + (size_t)row * D_DIM;
    dst = x2 + row;
  } else {
    int r = row - B_ROWS;
    src = emb + (size_t)r * D_DIM;
    dst = e2 + r;
  }
  float v = src[lane];
  float t = v * v;
  asm volatile("" : "+v"(t));  // keep fl(v*v) un-fused
  float acc = t;
#pragma unroll
  for (int i = 1; i < 16; ++i) {
    float w = src[i * 8 + lane];
    float tt = w * w;
    asm volatile("" : "+v"(tt));
    acc = acc + tt;
  }
  acc = acc + __shfl_xor(acc, 1, 64);
  acc = acc + __shfl_xor(acc, 2, 64);
  acc = acc + __shfl_xor(acc, 4, 64);
  if (lane == 0) *dst = acc;
}

// ---------------------------------------------------------------------------
// Kernel 2: two-phase MFMA argmin.
// Block: 512 threads (8 waves), 128 rows.  Per chunk of 128 codes: stage
// bf16 B-tile, MFMA 16x16x32 (wave covers 2 m-tiles x 4 n-tiles, A-frags
// hoisted in registers for the whole kernel).
// Pass A: per-row min of t~ = e2 - 2*dot~ (bf16 approx, fp32 accum).
// Pass B: collect candidates with t~ <= min + MARGIN into LDS lists.
// Phase 2: exact fp32 rescoring (bit-identical to the validated round-2
// pipeline) of candidates only; first-index tie-break.  Overflow rows
// (cnt > CAP) fall back to an exact full scan (expected: never).
// ---------------------------------------------------------------------------
__global__ __launch_bounds__(512) void vq_argmin_mfma(
    const float* __restrict__ x, const float* __restrict__ emb,
    const unsigned short* __restrict__ xb, const unsigned short* __restrict__ eb,
    const float* __restrict__ x2, const float* __restrict__ e2,
    float* __restrict__ out_idx) {
  __shared__ float smem[24064];                              // 94 KB
  unsigned short* AsU = (unsigned short*)smem;               // [128m][128k] bf16
  unsigned short* BsU = (unsigned short*)(smem + 8192);      // [128n][128k] bf16
  float* e2s = smem + 16384;                                 // [4096]
  float* m2 = smem + 20480;                                  // [128][2]
  float* mlim = smem + 20736;                                // [128]
  unsigned int* cnt = (unsigned int*)(smem + 20864);         // [128]
  unsigned short* lists = (unsigned short*)(smem + 20992);   // [128][CAP]
  float* redv = smem + 23040;                                // [512] fallback
  int* redi = (int*)(smem + 23552);                          // [512] fallback
  float* xf = smem;                                          // phase-2: [128][128] fp32
  int* fb = (int*)m2;                                        // phase-2: overflow flags

  const int tid = threadIdx.x;
  const int wid = tid >> 6, lane = tid & 63;
  const int q = lane >> 4, lr = lane & 15;
  const int mt0 = (wid >> 1) * 2;   // this wave: m-tiles mt0, mt0+1
  const int nq = (wid & 1) * 4;     // this wave: n-tiles nq..nq+3
  const int rowbase = blockIdx.x * 128;

  // ---- stage A-tile (bf16) and e2s ----
  {
    const uint4* src = (const uint4*)(xb + (size_t)rowbase * 128);
    uint4* dst = (uint4*)AsU;
#pragma unroll
    for (int p = 0; p < 4; ++p) dst[p * 512 + tid] = src[p * 512 + tid];
    ((float4*)e2s)[tid] = ((const float4*)e2)[tid];
    ((float4*)e2s)[tid + 512] = ((const float4*)e2)[tid + 512];
  }
  __syncthreads();

  // ---- hoist A fragments (constant across all chunks & both passes) ----
  bf16x8 af[2][4];
#pragma unroll
  for (int mi = 0; mi < 2; ++mi) {
    int m = (mt0 + mi) * 16 + lr;
#pragma unroll
    for (int ks = 0; ks < 4; ++ks)
      af[mi][ks] = *(const bf16x8*)(AsU + m * 128 + ks * 32 + q * 8);
  }

  float rm[2][4];
#pragma unroll
  for (int mi = 0; mi < 2; ++mi)
#pragma unroll
    for (int rg = 0; rg < 4; ++rg) rm[mi][rg] = 3.4e38f;

#pragma unroll 1
  for (int pass = 0; pass < 2; ++pass) {
    if (pass == 1) {
      if (tid < 128) cnt[tid] = 0;
      __syncthreads();
    }
#pragma unroll 1
    for (int ch = 0; ch < 32; ++ch) {
      {  // stage B chunk (128 codes x 128 k, bf16)
        const uint4* src = (const uint4*)(eb + (size_t)ch * 128 * 128);
        uint4* dst = (uint4*)BsU;
#pragma unroll
        for (int p = 0; p < 4; ++p) dst[p * 512 + tid] = src[p * 512 + tid];
      }
      __syncthreads();

      f32x4 acc[2][4];
#pragma unroll
      for (int mi = 0; mi < 2; ++mi)
#pragma unroll
        for (int ni = 0; ni < 4; ++ni) {
          f32x4 z = {0.f, 0.f, 0.f, 0.f};
          acc[mi][ni] = z;
        }
#pragma unroll
      for (int ks = 0; ks < 4; ++ks) {
        bf16x8 bf[4];
#pragma unroll
        for (int ni = 0; ni < 4; ++ni) {
          int n = (nq + ni) * 16 + lr;
          bf[ni] = *(const bf16x8*)(BsU + n * 128 + ks * 32 + q * 8);
        }
#pragma unroll
        for (int mi = 0; mi < 2; ++mi)
#pragma unroll
          for (int ni = 0; ni < 4; ++ni)
            acc[mi][ni] = __builtin_amdgcn_mfma_f32_16x16x32_bf16(
                af[mi][ks], bf[ni], acc[mi][ni], 0, 0, 0);
      }

      if (pass == 0) {
#pragma unroll
        for (int mi = 0; mi < 2; ++mi)
#pragma unroll
          for (int ni = 0; ni < 4; ++ni) {
            float ev = e2s[ch * 128 + (nq + ni) * 16 + lr];
#pragma unroll
            for (int rg = 0; rg < 4; ++rg) {
              float t = ev - 2.0f * acc[mi][ni][rg];
              rm[mi][rg] = fminf(rm[mi][rg], t);
            }
          }
      } else {
#pragma unroll
        for (int mi = 0; mi < 2; ++mi)
#pragma unroll
          for (int ni = 0; ni < 4; ++ni) {
            int col = ch * 128 + (nq + ni) * 16 + lr;
            float ev = e2s[col];
#pragma unroll
            for (int rg = 0; rg < 4; ++rg) {
              float t = ev - 2.0f * acc[mi][ni][rg];
              int row = (mt0 + mi) * 16 + q * 4 + rg;
              if (t <= mlim[row]) {
                unsigned int p = atomicAdd(&cnt[row], 1u);
                if (p < CAP) lists[row * CAP + p] = (unsigned short)col;
              }
            }
          }
      }
      __syncthreads();
    }

    if (pass == 0) {  // cross-lane min over the 16 col-lanes, then cross-wave
#pragma unroll
      for (int mi = 0; mi < 2; ++mi)
#pragma unroll
        for (int rg = 0; rg < 4; ++rg) {
          float v = rm[mi][rg];
          v = fminf(v, __shfl_xor(v, 1, 64));
          v = fminf(v, __shfl_xor(v, 2, 64));
          v = fminf(v, __shfl_xor(v, 4, 64));
          v = fminf(v, __shfl_xor(v, 8, 64));
          if (lr == 0) {
            int row = (mt0 + mi) * 16 + q * 4 + rg;
            m2[row * 2 + (wid & 1)] = v;
          }
        }
      __syncthreads();
      if (tid < 128) mlim[tid] = fminf(m2[tid * 2], m2[tid * 2 + 1]) + MARGIN;
      __syncthreads();
    }
  }

  // ---- phase 2: stage fp32 x rows (reuse As/Bs LDS), exact rescoring ----
  {
    const float4* src = (const float4*)(x + (size_t)rowbase * 128);
    float4* dst = (float4*)xf;
#pragma unroll
    for (int p = 0; p < 8; ++p) dst[p * 512 + tid] = src[p * 512 + tid];
  }
  __syncthreads();
  if (tid < 128) fb[tid] = (cnt[tid] > CAP) ? 1 : 0;
  __syncthreads();

  if (tid < 128 && !fb[tid]) {
    int r = tid;
    int c = (int)cnt[r];
    float xs2 = x2[rowbase + r];
    float best = 3.4e38f;
    int bidx = 0x7fffffff;
    for (int j = 0; j < c; ++j) {
      int col = lists[r * CAP + j];
      float dot = 0.f;
      const float4* ev = (const float4*)(emb + (size_t)col * 128);
      const float* xr = xf + r * 128;
#pragma unroll 8
      for (int d4 = 0; d4 < 32; ++d4) {  // exact ascending-d fmaf chain
        float4 e4 = ev[d4];
        dot = __builtin_fmaf(xr[d4 * 4 + 0], e4.x, dot);
        dot = __builtin_fmaf(xr[d4 * 4 + 1], e4.y, dot);
        dot = __builtin_fmaf(xr[d4 * 4 + 2], e4.z, dot);
        dot = __builtin_fmaf(xr[d4 * 4 + 3], e4.w, dot);
      }
      float t1 = xs2 + e2s[col];                 // fl(x2+e2)
      float s = __builtin_fmaf(-2.0f, dot, t1);  // fl(t1 - 2*dot)
      if (s < best || (s == best && col < bidx)) { best = s; bidx = col; }
    }
    out_idx[rowbase + r] = (float)bidx;
  }
  __syncthreads();

  // ---- overflow fallback: exact full scan (expected never) ----
  for (int r = 0; r < 128; ++r) {
    if (fb[r]) {
      float xs2 = x2[rowbase + r];
      float lbest = 3.4e38f;
      int lidx = 0x7fffffff;
      for (int c0 = tid; c0 < K_CODES; c0 += 512) {
        float dot = 0.f;
        const float4* ev = (const float4*)(emb + (size_t)c0 * 128);
        const float* xr = xf + r * 128;
        for (int d4 = 0; d4 < 32; ++d4) {
          float4 e4 = ev[d4];
          dot = __builtin_fmaf(xr[d4 * 4 + 0], e4.x, dot);
          dot = __builtin_fmaf(xr[d4 * 4 + 1], e4.y, dot);
          dot = __builtin_fmaf(xr[d4 * 4 + 2], e4.z, dot);
          dot = __builtin_fmaf(xr[d4 * 4 + 3], e4.w, dot);
        }
        float s = __builtin_fmaf(-2.0f, dot, xs2 + e2s[c0]);
        if (s < lbest || (s == lbest && c0 < lidx)) { lbest = s; lidx = c0; }
      }
      redv[tid] = lbest;
      redi[tid] = lidx;
      __syncthreads();
      if (tid == 0) {
        float bv = redv[0]; int bi = redi[0];
        for (int t = 1; t < 512; ++t) {
          float v = redv[t]; int i2 = redi[t];
          if (v < bv || (v == bv && i2 < bi)) { bv = v; bi = i2; }
        }
        out_idx[rowbase + r] = (float)bi;
      }
      __syncthreads();
    }
  }
}

// ---------------------------------------------------------------------------
// Kernel 3 (round-2 validated): gather + straight-through + losses + histogram.
// ---------------------------------------------------------------------------
__global__ __launch_bounds__(256) void vq_gather(const float* __restrict__ x,
                                                 const float* __restrict__ emb,
                                                 const float* __restrict__ idxf,
                                                 float* __restrict__ out_q,
                                                 unsigned int* __restrict__ counts,
                                                 double* __restrict__ sums) {
  int r = blockIdx.x * 8 + (threadIdx.x >> 5);
  int lane = threadIdx.x & 31;
  int idx = (int)idxf[r];
  const float4 q = *(const float4*)(emb + (size_t)idx * 128 + lane * 4);
  const float4 xv = *(const float4*)(x + (size_t)r * 128 + lane * 4);
  float d0 = q.x - xv.x, d1 = q.y - xv.y, d2 = q.z - xv.z, d3 = q.w - xv.w;
  float s0 = xv.x + d0, s1 = xv.y + d1, s2 = xv.z + d2, s3 = xv.w + d3;
  float4 st = make_float4(s0, s1, s2, s3);
  *(float4*)(out_q + (size_t)r * 128 + lane * 4) = st;
  float g0 = s0 - xv.x, g1 = s1 - xv.y, g2 = s2 - xv.z, g3 = s3 - xv.w;
  double es = (double)(d0 * d0) + (double)(d1 * d1) + (double)(d2 * d2) + (double)(d3 * d3);
  double qs = (double)(g0 * g0) + (double)(g1 * g1) + (double)(g2 * g2) + (double)(g3 * g3);
#pragma unroll
  for (int off = 32; off >= 1; off >>= 1) {
    es += __shfl_down(es, off, 64);
    qs += __shfl_down(qs, off, 64);
  }
  __shared__ double lred[2][4];
  int w = threadIdx.x >> 6;
  if ((threadIdx.x & 63) == 0) { lred[0][w] = es; lred[1][w] = qs; }
  if (lane == 0) atomicAdd(&counts[idx], 1u);
  __syncthreads();
  if (threadIdx.x == 0) {
    double e = lred[0][0] + lred[0][1] + lred[0][2] + lred[0][3];
    double qq = lred[1][0] + lred[1][1] + lred[1][2] + lred[1][3];
    atomicAdd(&sums[0], e);
    atomicAdd(&sums[1], qq);
  }
}

// ---------------------------------------------------------------------------
// Kernel 4 (round-2 validated): finalize scalars.
// ---------------------------------------------------------------------------
__global__ __launch_bounds__(256) void vq_final(const unsigned int* __restrict__ counts,
                                                const double* __restrict__ sums,
                                                float* __restrict__ out_scalars) {
  double s = 0.0;
  for (int k = threadIdx.x; k < K_CODES; k += 256) {
    float p = (float)counts[k] * (1.0f / 32768.0f);
    float term = p * logf(p + 1e-10f);
    s += (double)term;
  }
#pragma unroll
  for (int off = 32; off >= 1; off >>= 1) s += __shfl_down(s, off, 64);
  __shared__ double red[4];
  if ((threadIdx.x & 63) == 0) red[threadIdx.x >> 6] = s;
  __syncthreads();
  if (threadIdx.x == 0) {
    double tot = red[0] + red[1] + red[2] + red[3];
    float e_lat = (float)(sums[0] / (double)(B_ROWS * D_DIM));
    float q_lat = (float)(sums[1] / (double)(B_ROWS * D_DIM));
    float vq = q_lat + 0.25f * e_lat;
    out_scalars[0] = vq;
    out_scalars[1] = e_lat;
    out_scalars[2] = q_lat;
    out_scalars[3] = expf(-(float)tot);
  }
}

extern "C" void kernel_launch(void* const* d_in, const int* in_sizes, int n_in,
                              void* d_out, int out_size, void* d_ws, size_t ws_size,
                              hipStream_t stream) {
  const float* x = (const float*)d_in[0];
  const float* emb = (const float*)d_in[1];
  float* out = (float*)d_out;

  // ws: counts[4096] u32 @0 | sums[2] f64 @16384 | e2 @16400 | x2 @32784
  unsigned int* counts = (unsigned int*)d_ws;
  double* sums = (double*)((char*)d_ws + 16384);
  float* e2 = (float*)((char*)d_ws + 16400);
  float* x2 = (float*)((char*)d_ws + 16400 + 4 * K_CODES);

  // bf16 scratch lives in d_out's quantized region (overwritten later by
  // vq_gather, which runs after vq_argmin_mfma has consumed it).
  unsigned short* xb = (unsigned short*)out;                  // 8 MB
  unsigned short* eb = (unsigned short*)(out + 2097152);      // 1 MB

  float* out_idx = out + (size_t)B_ROWS * D_DIM;
  float* out_scalars = out_idx + B_ROWS;

  hipMemsetAsync(d_ws, 0, 16400, stream);  // zero counts + sums
  cast_bf16<<<2304, 256, 0, stream>>>(x, emb, xb, eb);
  sq_rows<<<(B_ROWS + K_CODES) / 32, 256, 0, stream>>>(x, emb, x2, e2);
  vq_argmin_mfma<<<B_ROWS / 128, 512, 0, stream>>>(x, emb, xb, eb, x2, e2, out_idx);
  vq_gather<<<B_ROWS / 8, 256, 0, stream>>>(x, emb, out_idx, out, counts, sums);
  vq_final<<<1, 256, 0, stream>>>(counts, sums, out_scalars);
}

// Round 5
// 366.232 us; speedup vs baseline: 1.7383x; 1.4319x over previous
//
#include <hip/hip_runtime.h>
#include <math.h>

#define B_ROWS 32768
#define K_CODES 4096
#define D_DIM 128
#define MARGIN 1.5e-3f
#define CAP 32

typedef short bf16x8 __attribute__((ext_vector_type(8)));
typedef float f32x4 __attribute__((ext_vector_type(4)));

// RNE float->bf16 (finite inputs only)
__device__ __forceinline__ unsigned short f2bf(float f) {
  union { float f; unsigned int u; } v; v.f = f;
  unsigned int r = (v.u + 0x7FFFu + ((v.u >> 16) & 1u)) >> 16;
  return (unsigned short)r;
}

// ---------------------------------------------------------------------------
// Kernel 1: prep — x2/e2 (numpy pairwise order, validated) + eb bf16 cast.
// ---------------------------------------------------------------------------
__global__ __launch_bounds__(256) void prep(const float* __restrict__ x,
                                            const float* __restrict__ emb,
                                            float* __restrict__ x2,
                                            float* __restrict__ e2,
                                            unsigned short* __restrict__ ebb) {
  const int t0 = blockIdx.x * 256 + threadIdx.x;
  const int stride = gridDim.x * 256;
  // (a) x2: 8 lanes/row; accumulator j sums fl(x_{8i+j}^2) in order i=0..15,
  // then shfl-xor 1,2,4 = ((r0+r1)+(r2+r3))+((r4+r5)+(r6+r7)).
  for (int s = t0; s < B_ROWS * 8; s += stride) {
    int row = s >> 3, lane = s & 7;
    const float* src = x + (size_t)row * D_DIM;
    float v = src[lane];
    float t = v * v;
    asm volatile("" : "+v"(t));  // keep fl(v*v) un-fused
    float acc = t;
#pragma unroll
    for (int i = 1; i < 16; ++i) {
      float w = src[i * 8 + lane];
      float tt = w * w;
      asm volatile("" : "+v"(tt));
      acc = acc + tt;
    }
    acc = acc + __shfl_xor(acc, 1, 64);
    acc = acc + __shfl_xor(acc, 2, 64);
    acc = acc + __shfl_xor(acc, 4, 64);
    if (lane == 0) x2[row] = acc;
  }
  // (b) e2, same recipe
  for (int s = t0; s < K_CODES * 8; s += stride) {
    int row = s >> 3, lane = s & 7;
    const float* src = emb + (size_t)row * D_DIM;
    float v = src[lane];
    float t = v * v;
    asm volatile("" : "+v"(t));
    float acc = t;
#pragma unroll
    for (int i = 1; i < 16; ++i) {
      float w = src[i * 8 + lane];
      float tt = w * w;
      asm volatile("" : "+v"(tt));
      acc = acc + tt;
    }
    acc = acc + __shfl_xor(acc, 1, 64);
    acc = acc + __shfl_xor(acc, 2, 64);
    acc = acc + __shfl_xor(acc, 4, 64);
    if (lane == 0) e2[row] = acc;
  }
  // (c) emb -> bf16 cast (8 elems per group)
  for (int g = t0; g < K_CODES * D_DIM / 8; g += stride) {
    float4 a = ((const float4*)emb)[g * 2];
    float4 b = ((const float4*)emb)[g * 2 + 1];
    ushort4 o0 = make_ushort4(f2bf(a.x), f2bf(a.y), f2bf(a.z), f2bf(a.w));
    ushort4 o1 = make_ushort4(f2bf(b.x), f2bf(b.y), f2bf(b.z), f2bf(b.w));
    ((ushort4*)ebb)[g * 2] = o0;
    ((ushort4*)ebb)[g * 2 + 1] = o1;
  }
}

// ---------------------------------------------------------------------------
// Kernel 2: fused two-phase MFMA argmin + exact rescore + gather/losses.
// 256 threads (4 waves), 64 rows/block, 512 blocks (2-3/CU).
// A-fragments: cast from fp32 x in-kernel, hoisted in regs for the whole
// kernel.  B-fragments: read DIRECTLY from eb in global (L2-resident, 1 MB)
// -> no LDS staging, no bank conflicts, NO per-chunk barriers.
// Pass A: per-row min of t~ = fmaf(-2,dot~,e2).  Pass B: collect candidates
// t~ <= min+MARGIN.  Phase 2: exact fp32 rescore (validated bit-exact chain),
// first-index tie-break; overflow rows -> exact full scan.  Epilogue: gather
// quantized rows, straight-through output, loss partials, histogram counts.
// ---------------------------------------------------------------------------
__global__ __launch_bounds__(256, 2) void vq_main(
    const float* __restrict__ x, const float* __restrict__ emb,
    const unsigned short* __restrict__ eb,
    const float* __restrict__ x2g, const float* __restrict__ e2g,
    float* __restrict__ out_q, float* __restrict__ out_idx,
    unsigned int* __restrict__ counts, double* __restrict__ sums) {
  __shared__ float smem[13776];
  float* e2s = smem;                                   // [4096]
  float* xf = smem + 4096;                             // [64][132] padded fp32
  float* m2 = smem + 4096;                             // overlay (dead pre-xf)
  unsigned short* lists = (unsigned short*)(smem + 12544);  // [64][CAP]
  float* redv = smem + 12544;                          // overlay lists (fallback)
  int* redi = (int*)(smem + 12800);
  float* mlims = smem + 13568;                         // [64]
  unsigned int* cnt = (unsigned int*)(smem + 13632);   // [64]
  int* bidxs = (int*)(smem + 13696);                   // [64]
  double* lred = (double*)(smem + 13760);              // [8]

  const int tid = threadIdx.x;
  const int wid = tid >> 6;        // 0..3 -> n-tiles wid*2, wid*2+1
  const int lane = tid & 63;
  const int q = lane >> 4, lr = lane & 15;
  const int rowbase = blockIdx.x * 64;

  // stage e2s
#pragma unroll
  for (int p = 0; p < 4; ++p)
    ((float4*)e2s)[p * 256 + tid] = ((const float4*)e2g)[p * 256 + tid];

  // hoist A fragments: af[mi][ks] = bf16(x[rowbase+mi*16+lr][ks*32+q*8 ..+7])
  bf16x8 af[4][4];
#pragma unroll
  for (int mi = 0; mi < 4; ++mi) {
    const float* xr = x + (size_t)(rowbase + mi * 16 + lr) * D_DIM;
#pragma unroll
    for (int ks = 0; ks < 4; ++ks) {
      float4 v0 = *(const float4*)(xr + ks * 32 + q * 8);
      float4 v1 = *(const float4*)(xr + ks * 32 + q * 8 + 4);
      bf16x8 f;
      f[0] = (short)f2bf(v0.x); f[1] = (short)f2bf(v0.y);
      f[2] = (short)f2bf(v0.z); f[3] = (short)f2bf(v0.w);
      f[4] = (short)f2bf(v1.x); f[5] = (short)f2bf(v1.y);
      f[6] = (short)f2bf(v1.z); f[7] = (short)f2bf(v1.w);
      af[mi][ks] = f;
    }
  }
  __syncthreads();  // e2s ready

  // ---------------- pass A: global min of t~ per row ----------------
  float rm[4][4];
#pragma unroll
  for (int mi = 0; mi < 4; ++mi)
#pragma unroll
    for (int rg = 0; rg < 4; ++rg) rm[mi][rg] = 3.4e38f;

#pragma unroll 2
  for (int ch = 0; ch < 32; ++ch) {
    bf16x8 bf[2][4];
#pragma unroll
    for (int ni = 0; ni < 2; ++ni) {
      const unsigned short* er =
          eb + (size_t)(ch * 128 + (wid * 2 + ni) * 16 + lr) * D_DIM;
#pragma unroll
      for (int ks = 0; ks < 4; ++ks)
        bf[ni][ks] = *(const bf16x8*)(er + ks * 32 + q * 8);
    }
    f32x4 acc[4][2];
#pragma unroll
    for (int mi = 0; mi < 4; ++mi)
#pragma unroll
      for (int ni = 0; ni < 2; ++ni) {
        f32x4 z = {0.f, 0.f, 0.f, 0.f};
        acc[mi][ni] = z;
      }
#pragma unroll
    for (int ks = 0; ks < 4; ++ks)
#pragma unroll
      for (int mi = 0; mi < 4; ++mi)
#pragma unroll
        for (int ni = 0; ni < 2; ++ni)
          acc[mi][ni] = __builtin_amdgcn_mfma_f32_16x16x32_bf16(
              af[mi][ks], bf[ni][ks], acc[mi][ni], 0, 0, 0);
#pragma unroll
    for (int ni = 0; ni < 2; ++ni) {
      float ev = e2s[ch * 128 + (wid * 2 + ni) * 16 + lr];
#pragma unroll
      for (int mi = 0; mi < 4; ++mi)
#pragma unroll
        for (int rg = 0; rg < 4; ++rg) {
          float t = __builtin_fmaf(-2.0f, acc[mi][ni][rg], ev);
          rm[mi][rg] = fminf(rm[mi][rg], t);
        }
    }
  }

  // reduce min across the 16 col-lanes, then across the 4 waves
#pragma unroll
  for (int mi = 0; mi < 4; ++mi)
#pragma unroll
    for (int rg = 0; rg < 4; ++rg) {
      float v = rm[mi][rg];
      v = fminf(v, __shfl_xor(v, 1, 64));
      v = fminf(v, __shfl_xor(v, 2, 64));
      v = fminf(v, __shfl_xor(v, 4, 64));
      v = fminf(v, __shfl_xor(v, 8, 64));
      if (lr == 0) m2[(mi * 16 + q * 4 + rg) * 4 + wid] = v;
    }
  __syncthreads();
  if (tid < 64) {
    float a = fminf(m2[tid * 4], m2[tid * 4 + 1]);
    float b = fminf(m2[tid * 4 + 2], m2[tid * 4 + 3]);
    mlims[tid] = fminf(a, b) + MARGIN;
    cnt[tid] = 0;
  }
  __syncthreads();

  // ---------------- pass B: collect candidates ----------------
  float ml[4][4];
#pragma unroll
  for (int mi = 0; mi < 4; ++mi)
#pragma unroll
    for (int rg = 0; rg < 4; ++rg) ml[mi][rg] = mlims[mi * 16 + q * 4 + rg];

#pragma unroll 2
  for (int ch = 0; ch < 32; ++ch) {
    bf16x8 bf[2][4];
#pragma unroll
    for (int ni = 0; ni < 2; ++ni) {
      const unsigned short* er =
          eb + (size_t)(ch * 128 + (wid * 2 + ni) * 16 + lr) * D_DIM;
#pragma unroll
      for (int ks = 0; ks < 4; ++ks)
        bf[ni][ks] = *(const bf16x8*)(er + ks * 32 + q * 8);
    }
    f32x4 acc[4][2];
#pragma unroll
    for (int mi = 0; mi < 4; ++mi)
#pragma unroll
      for (int ni = 0; ni < 2; ++ni) {
        f32x4 z = {0.f, 0.f, 0.f, 0.f};
        acc[mi][ni] = z;
      }
#pragma unroll
    for (int ks = 0; ks < 4; ++ks)
#pragma unroll
      for (int mi = 0; mi < 4; ++mi)
#pragma unroll
        for (int ni = 0; ni < 2; ++ni)
          acc[mi][ni] = __builtin_amdgcn_mfma_f32_16x16x32_bf16(
              af[mi][ks], bf[ni][ks], acc[mi][ni], 0, 0, 0);
#pragma unroll
    for (int ni = 0; ni < 2; ++ni) {
      int colbase = ch * 128 + (wid * 2 + ni) * 16 + lr;
      float ev = e2s[colbase];
#pragma unroll
      for (int mi = 0; mi < 4; ++mi)
#pragma unroll
        for (int rg = 0; rg < 4; ++rg) {
          float t = __builtin_fmaf(-2.0f, acc[mi][ni][rg], ev);
          if (t <= ml[mi][rg]) {
            int row = mi * 16 + q * 4 + rg;
            unsigned int p = atomicAdd(&cnt[row], 1u);
            if (p < CAP) lists[row * CAP + p] = (unsigned short)colbase;
          }
        }
    }
  }

  // ---------------- phase 2: stage fp32 x rows, exact rescore ----------------
  __syncthreads();  // lists/cnt final; m2 dead -> xf may be written
  {
    const float4* src = (const float4*)(x + (size_t)rowbase * D_DIM);
#pragma unroll
    for (int p = 0; p < 8; ++p) {
      int idx = p * 256 + tid;            // float4 index over 64x128
      int r = idx >> 5, c = idx & 31;     // row, float4-col
      *(float4*)(xf + r * 132 + c * 4) = src[idx];
    }
  }
  __syncthreads();

  if (tid < 64 && cnt[tid] <= CAP) {
    int c = (int)cnt[tid];
    float xs2 = x2g[rowbase + tid];
    float best = 3.4e38f;
    int bidx = 0x7fffffff;
    const float* xr = xf + tid * 132;
    for (int j = 0; j < c; ++j) {
      int col = lists[tid * CAP + j];
      float dot = 0.f;
      const float4* ev = (const float4*)(emb + (size_t)col * D_DIM);
#pragma unroll 8
      for (int d4 = 0; d4 < 32; ++d4) {  // exact ascending-d fmaf chain
        float4 e4 = ev[d4];
        dot = __builtin_fmaf(xr[d4 * 4 + 0], e4.x, dot);
        dot = __builtin_fmaf(xr[d4 * 4 + 1], e4.y, dot);
        dot = __builtin_fmaf(xr[d4 * 4 + 2], e4.z, dot);
        dot = __builtin_fmaf(xr[d4 * 4 + 3], e4.w, dot);
      }
      float t1 = xs2 + e2s[col];                 // fl(x2+e2)
      float s = __builtin_fmaf(-2.0f, dot, t1);  // fl(t1 - 2*dot)
      if (s < best || (s == best && col < bidx)) { best = s; bidx = col; }
    }
    out_idx[rowbase + tid] = (float)bidx;
    bidxs[tid] = bidx;
    atomicAdd(&counts[bidx], 1u);
  }
  __syncthreads();

  // overflow fallback: exact full scan (expected never); cnt[r] block-uniform
  for (int r = 0; r < 64; ++r) {
    if (cnt[r] <= CAP) continue;
    float xs2 = x2g[rowbase + r];
    const float* xr = xf + r * 132;
    float lbest = 3.4e38f;
    int lidx = 0x7fffffff;
    for (int c0 = tid; c0 < K_CODES; c0 += 256) {
      float dot = 0.f;
      const float4* ev = (const float4*)(emb + (size_t)c0 * D_DIM);
      for (int d4 = 0; d4 < 32; ++d4) {
        float4 e4 = ev[d4];
        dot = __builtin_fmaf(xr[d4 * 4 + 0], e4.x, dot);
        dot = __builtin_fmaf(xr[d4 * 4 + 1], e4.y, dot);
        dot = __builtin_fmaf(xr[d4 * 4 + 2], e4.z, dot);
        dot = __builtin_fmaf(xr[d4 * 4 + 3], e4.w, dot);
      }
      float s = __builtin_fmaf(-2.0f, dot, xs2 + e2s[c0]);
      if (s < lbest || (s == lbest && c0 < lidx)) { lbest = s; lidx = c0; }
    }
    redv[tid] = lbest;
    redi[tid] = lidx;
    __syncthreads();
    if (tid == 0) {
      float bv = redv[0]; int bi = redi[0];
      for (int t = 1; t < 256; ++t) {
        float v = redv[t]; int i2 = redi[t];
        if (v < bv || (v == bv && i2 < bi)) { bv = v; bi = i2; }
      }
      out_idx[rowbase + r] = (float)bi;
      bidxs[r] = bi;
      atomicAdd(&counts[bi], 1u);
    }
    __syncthreads();
  }
  __syncthreads();  // bidxs ready for all rows

  // ---------------- fused gather + straight-through + losses ----------------
  // st = fl(x + fl(q-x)); e-term fl((q-x)^2), q-term fl((st-x)^2); dbl accum.
  {
    int gr = tid >> 2, seg = tid & 3;
    int gidx = bidxs[gr];
    const float4* ev = (const float4*)(emb + (size_t)gidx * D_DIM + seg * 32);
    const float* xvp = xf + gr * 132 + seg * 32;
    float4* oq = (float4*)(out_q + (size_t)(rowbase + gr) * D_DIM + seg * 32);
    double es = 0.0, qs = 0.0;
#pragma unroll
    for (int j = 0; j < 8; ++j) {
      float4 e4 = ev[j];
      float4 xv = *(const float4*)(xvp + j * 4);
      float d0 = e4.x - xv.x, d1 = e4.y - xv.y, d2 = e4.z - xv.z, d3 = e4.w - xv.w;
      float s0 = xv.x + d0, s1 = xv.y + d1, s2 = xv.z + d2, s3 = xv.w + d3;
      oq[j] = make_float4(s0, s1, s2, s3);
      float g0 = s0 - xv.x, g1 = s1 - xv.y, g2 = s2 - xv.z, g3 = s3 - xv.w;
      es += (double)(d0 * d0) + (double)(d1 * d1) + (double)(d2 * d2) + (double)(d3 * d3);
      qs += (double)(g0 * g0) + (double)(g1 * g1) + (double)(g2 * g2) + (double)(g3 * g3);
    }
#pragma unroll
    for (int off = 32; off >= 1; off >>= 1) {
      es += __shfl_down(es, off, 64);
      qs += __shfl_down(qs, off, 64);
    }
    if (lane == 0) { lred[wid * 2] = es; lred[wid * 2 + 1] = qs; }
    __syncthreads();
    if (tid == 0) {
      double e = lred[0] + lred[2] + lred[4] + lred[6];
      double qq = lred[1] + lred[3] + lred[5] + lred[7];
      atomicAdd(&sums[0], e);
      atomicAdd(&sums[1], qq);
    }
  }
}

// ---------------------------------------------------------------------------
// Kernel 3 (validated): finalize scalars.
// ---------------------------------------------------------------------------
__global__ __launch_bounds__(256) void vq_final(const unsigned int* __restrict__ counts,
                                                const double* __restrict__ sums,
                                                float* __restrict__ out_scalars) {
  double s = 0.0;
  for (int k = threadIdx.x; k < K_CODES; k += 256) {
    float p = (float)counts[k] * (1.0f / 32768.0f);
    float term = p * logf(p + 1e-10f);
    s += (double)term;
  }
#pragma unroll
  for (int off = 32; off >= 1; off >>= 1) s += __shfl_down(s, off, 64);
  __shared__ double red[4];
  if ((threadIdx.x & 63) == 0) red[threadIdx.x >> 6] = s;
  __syncthreads();
  if (threadIdx.x == 0) {
    double tot = red[0] + red[1] + red[2] + red[3];
    float e_lat = (float)(sums[0] / (double)(B_ROWS * D_DIM));
    float q_lat = (float)(sums[1] / (double)(B_ROWS * D_DIM));
    float vq = q_lat + 0.25f * e_lat;   // fl(q + fl(0.25*e)); 0.25*e exact
    out_scalars[0] = vq;
    out_scalars[1] = e_lat;
    out_scalars[2] = q_lat;
    out_scalars[3] = expf(-(float)tot);
  }
}

extern "C" void kernel_launch(void* const* d_in, const int* in_sizes, int n_in,
                              void* d_out, int out_size, void* d_ws, size_t ws_size,
                              hipStream_t stream) {
  const float* x = (const float*)d_in[0];
  const float* emb = (const float*)d_in[1];
  float* out = (float*)d_out;

  // ws: counts[4096]u32 @0 | sums[2]f64 @16384 | x2[32768] @16400 |
  //     e2[4096] @147472 | eb[4096*128]u16 @163856   (~1.21 MB total)
  unsigned int* counts = (unsigned int*)d_ws;
  double* sums = (double*)((char*)d_ws + 16384);
  float* x2 = (float*)((char*)d_ws + 16400);
  float* e2 = (float*)((char*)d_ws + 147472);
  unsigned short* eb = (unsigned short*)((char*)d_ws + 163856);

  float* out_idx = out + (size_t)B_ROWS * D_DIM;
  float* out_scalars = out_idx + B_ROWS;

  hipMemsetAsync(d_ws, 0, 16400, stream);  // zero counts + sums
  prep<<<512, 256, 0, stream>>>(x, emb, x2, e2, eb);
  vq_main<<<B_ROWS / 64, 256, 0, stream>>>(x, emb, eb, x2, e2, out, out_idx,
                                           counts, sums);
  vq_final<<<1, 256, 0, stream>>>(counts, sums, out_scalars);
}